// Round 1
// baseline (173.235 us; speedup 1.0000x reference)
//
#include <hip/hip_runtime.h>
#include <hip/hip_bf16.h>
#include <stdint.h>

#define D_DIM 1024
#define B_DIM 8
#define S_DIM 1024

typedef __bf16 bf16;
typedef __bf16 bf16x4 __attribute__((ext_vector_type(4)));
typedef __bf16 bf16x8 __attribute__((ext_vector_type(8)));
typedef float floatx4 __attribute__((ext_vector_type(4)));

__device__ __forceinline__ void async_copy16(const void* g, void* l) {
    __builtin_amdgcn_global_load_lds(
        (const __attribute__((address_space(1))) void*)g,
        (__attribute__((address_space(3))) void*)l, 16, 0, 0);
}

// ---------------------------------------------------------------------------
// Kernel 1: cast head/dep fp32->bf16 and compute s_head/s_dep projections.
// One block per row. Rows [0, B*S) = head, [B*S, 2*B*S) = dep.
// ---------------------------------------------------------------------------
__global__ __launch_bounds__(256) void cast_proj_kernel(
    const float* __restrict__ head, const float* __restrict__ dep,
    const float* __restrict__ edge_W,
    bf16* __restrict__ head_b, bf16* __restrict__ dep_b,
    float* __restrict__ s_head, float* __restrict__ s_dep)
{
    int row = blockIdx.x;
    const float* src;
    bf16* dst;
    const float* w;
    float* sout;
    if (row < B_DIM * S_DIM) {
        src  = head   + (size_t)row * D_DIM;
        dst  = head_b + (size_t)row * D_DIM;
        w    = edge_W;             // w[:D]
        sout = s_head + row;
    } else {
        int r = row - B_DIM * S_DIM;
        src  = dep   + (size_t)r * D_DIM;
        dst  = dep_b + (size_t)r * D_DIM;
        w    = edge_W + D_DIM;     // w[D:]
        sout = s_dep + r;
    }
    int t = threadIdx.x;                 // 256 threads * 4 floats = 1024
    float4 v  = ((const float4*)src)[t];
    float4 wv = ((const float4*)w)[t];

    bf16x4 o;
    o[0] = (bf16)v.x; o[1] = (bf16)v.y; o[2] = (bf16)v.z; o[3] = (bf16)v.w;
    ((bf16x4*)dst)[t] = o;

    float d = v.x * wv.x + v.y * wv.y + v.z * wv.z + v.w * wv.w;
    // wave64 reduce
    #pragma unroll
    for (int off = 32; off > 0; off >>= 1)
        d += __shfl_down(d, off, 64);
    __shared__ float red[4];
    int wid = t >> 6, lane = t & 63;
    if (lane == 0) red[wid] = d;
    __syncthreads();
    if (t == 0) *sout = red[0] + red[1] + red[2] + red[3];
}

// ---------------------------------------------------------------------------
// Kernel 2: Ut[k][d] = (bf16) U[d][k]   (so GEMM1 becomes A*B^T, K-contiguous)
// ---------------------------------------------------------------------------
__global__ __launch_bounds__(256) void transpose_cast_U(
    const float* __restrict__ U, bf16* __restrict__ Ut)
{
    __shared__ float tile[32][33];
    int bx = blockIdx.x * 32;  // k-block in output
    int by = blockIdx.y * 32;  // d-block in output
    int tx = threadIdx.x & 31;
    int ty4 = (threadIdx.x >> 5) * 4;
    #pragma unroll
    for (int i = 0; i < 4; ++i)
        tile[ty4 + i][tx] = U[(size_t)(by + ty4 + i) * D_DIM + bx + tx];
    __syncthreads();
    // Ut[bx+r][by+c] = U[by+c][bx+r] = tile[c][r]
    #pragma unroll
    for (int i = 0; i < 4; ++i)
        Ut[(size_t)(bx + ty4 + i) * D_DIM + by + tx] = (bf16)tile[tx][ty4 + i];
}

// ---------------------------------------------------------------------------
// GEMM: C[m][n] = sum_k A[m][k] * Bt[n][k]   (both operands K-contiguous)
// 128x128 tile, BK=64, 256 threads (4 waves in 2x2), 16x16x32 bf16 MFMA,
// global_load_lds width-16 staging (m97 structure).
// EPI=0: store bf16 (intermediate tmp).
// EPI=1: store fp32 + s_row[m] + s_col[n] + bias.
// Batched via blockIdx.z with strides sA/sB/sC (elements).
// ---------------------------------------------------------------------------
template <int EPI>
__global__ __launch_bounds__(256) void gemm_bt_kernel(
    const bf16* __restrict__ A, const bf16* __restrict__ Bt,
    void* __restrict__ Cout,
    int M, int N, int K,
    long long sA, long long sB, long long sC,
    const float* __restrict__ s_row, const float* __restrict__ s_col,
    const float* __restrict__ bias)
{
    const int BK = 64;
    __shared__ bf16 As[128 * BK];   // 16 KB
    __shared__ bf16 Bs[128 * BK];   // 16 KB

    int tid  = threadIdx.x;
    int wid  = tid >> 6;
    int lane = tid & 63;
    int quad = lane >> 4;
    int l16  = lane & 15;
    int wr   = wid >> 1;   // wave row (0..1) -> 64 rows
    int wc   = wid & 1;    // wave col (0..1) -> 64 cols

    int tile_m = blockIdx.y * 128;
    int tile_n = blockIdx.x * 128;
    int bz     = blockIdx.z;

    const bf16* Ab = A  + (size_t)bz * sA + (size_t)tile_m * K;
    const bf16* Bb = Bt + (size_t)bz * sB + (size_t)tile_n * K;

    floatx4 zero = {0.0f, 0.0f, 0.0f, 0.0f};
    floatx4 acc[4][4];
    #pragma unroll
    for (int i = 0; i < 4; ++i)
        #pragma unroll
        for (int j = 0; j < 4; ++j) acc[i][j] = zero;

    for (int k0 = 0; k0 < K; k0 += BK) {
        // ---- stage A and B tiles: 1024 granules of 16B each per tile ----
        // granule g -> row = g>>3 (8 granules of 8 bf16 per 64-elem row)
        #pragma unroll
        for (int it = 0; it < 4; ++it) {
            int g  = wid * 256 + it * 64 + lane;
            int r  = g >> 3;
            int cg = g & 7;
            int ldsoff = (wid * 256 + it * 64) * 8;  // wave-uniform, elements
            async_copy16(Ab + (size_t)r * K + k0 + cg * 8, &As[ldsoff]);
            async_copy16(Bb + (size_t)r * K + k0 + cg * 8, &Bs[ldsoff]);
        }
        __syncthreads();   // drains vmcnt -> staging complete

        #pragma unroll
        for (int kk = 0; kk < BK; kk += 32) {
            bf16x8 a[4], b[4];
            #pragma unroll
            for (int mt = 0; mt < 4; ++mt)
                a[mt] = *(const bf16x8*)&As[(wr * 64 + mt * 16 + l16) * BK + kk + quad * 8];
            #pragma unroll
            for (int nt = 0; nt < 4; ++nt)
                b[nt] = *(const bf16x8*)&Bs[(wc * 64 + nt * 16 + l16) * BK + kk + quad * 8];
            #pragma unroll
            for (int mt = 0; mt < 4; ++mt)
                #pragma unroll
                for (int nt = 0; nt < 4; ++nt)
                    acc[mt][nt] = __builtin_amdgcn_mfma_f32_16x16x32_bf16(
                        a[mt], b[nt], acc[mt][nt], 0, 0, 0);
        }
        __syncthreads();   // all reads done before next-iter staging
    }

    // ---- epilogue: C/D layout col = lane&15, row = quad*4 + reg ----
    int row0 = tile_m + wr * 64;
    int col0 = tile_n + wc * 64;
    if (EPI == 0) {
        bf16* Cb = (bf16*)Cout + (size_t)bz * sC;
        #pragma unroll
        for (int mt = 0; mt < 4; ++mt)
            #pragma unroll
            for (int r = 0; r < 4; ++r) {
                int row = row0 + mt * 16 + quad * 4 + r;
                #pragma unroll
                for (int nt = 0; nt < 4; ++nt) {
                    int col = col0 + nt * 16 + l16;
                    Cb[(size_t)row * N + col] = (bf16)acc[mt][nt][r];
                }
            }
    } else {
        float* Cf = (float*)Cout + (size_t)bz * sC;
        float b0 = bias[0];
        const float* srow = s_row + (size_t)bz * S_DIM;
        const float* scol = s_col + (size_t)bz * S_DIM;
        #pragma unroll
        for (int mt = 0; mt < 4; ++mt)
            #pragma unroll
            for (int r = 0; r < 4; ++r) {
                int row = row0 + mt * 16 + quad * 4 + r;
                float sh = srow[row] + b0;
                #pragma unroll
                for (int nt = 0; nt < 4; ++nt) {
                    int col = col0 + nt * 16 + l16;
                    Cf[(size_t)row * N + col] = acc[mt][nt][r] + sh + scol[col];
                }
            }
    }
}

// ---------------------------------------------------------------------------
extern "C" void kernel_launch(void* const* d_in, const int* in_sizes, int n_in,
                              void* d_out, int out_size, void* d_ws, size_t ws_size,
                              hipStream_t stream) {
    const float* head   = (const float*)d_in[0];
    const float* dep    = (const float*)d_in[1];
    const float* edge_U = (const float*)d_in[2];
    const float* edge_W = (const float*)d_in[3];
    const float* edge_b = (const float*)d_in[4];
    float* out = (float*)d_out;

    char* ws = (char*)d_ws;
    const size_t nBSD = (size_t)B_DIM * S_DIM * D_DIM;   // 8.39M elems

    bf16*  head_b = (bf16*)ws;  ws += nBSD * sizeof(bf16);               // 16 MB
    bf16*  dep_b  = (bf16*)ws;  ws += nBSD * sizeof(bf16);               // 16 MB
    bf16*  Ut     = (bf16*)ws;  ws += (size_t)D_DIM * D_DIM * sizeof(bf16); // 2 MB
    bf16*  tmp_b  = (bf16*)ws;  ws += nBSD * sizeof(bf16);               // 16 MB
    float* s_head = (float*)ws; ws += (size_t)B_DIM * S_DIM * sizeof(float);
    float* s_dep  = (float*)ws; ws += (size_t)B_DIM * S_DIM * sizeof(float);

    // 1. cast + projections
    cast_proj_kernel<<<2 * B_DIM * S_DIM, 256, 0, stream>>>(
        head, dep, edge_W, head_b, dep_b, s_head, s_dep);

    // 2. U^T cast
    transpose_cast_U<<<dim3(32, 32), 256, 0, stream>>>(edge_U, Ut);

    // 3. tmp[b,i,k] = sum_d head[b,i,d] * U[d,k]  ->  [8192 x 1024] * Ut^T
    gemm_bt_kernel<0><<<dim3(D_DIM / 128, (B_DIM * S_DIM) / 128, 1), 256, 0, stream>>>(
        head_b, Ut, tmp_b, B_DIM * S_DIM, D_DIM, D_DIM,
        0, 0, 0, nullptr, nullptr, nullptr);

    // 4. out[b,i,j] = sum_k tmp[b,i,k] * dep[b,j,k] + s_head + s_dep + bias
    gemm_bt_kernel<1><<<dim3(S_DIM / 128, S_DIM / 128, B_DIM), 256, 0, stream>>>(
        tmp_b, dep_b, out, S_DIM, S_DIM, D_DIM,
        (long long)S_DIM * D_DIM, (long long)S_DIM * D_DIM,
        (long long)S_DIM * S_DIM,
        s_head, s_dep, edge_b);
}

// Round 2
// 163.821 us; speedup vs baseline: 1.0575x; 1.0575x over previous
//
#include <hip/hip_runtime.h>
#include <hip/hip_bf16.h>
#include <stdint.h>

#define D_DIM 1024
#define B_DIM 8
#define S_DIM 1024

typedef __bf16 bf16;
typedef __bf16 bf16x4 __attribute__((ext_vector_type(4)));
typedef __bf16 bf16x8 __attribute__((ext_vector_type(8)));
typedef float floatx4 __attribute__((ext_vector_type(4)));

__device__ __forceinline__ void async_copy16(const void* g, void* l) {
    __builtin_amdgcn_global_load_lds(
        (const __attribute__((address_space(1))) void*)g,
        (__attribute__((address_space(3))) void*)l, 16, 0, 0);
}

// ---------------------------------------------------------------------------
// Kernel 1: cast head/dep fp32->bf16 + s_head/s_dep projections.
// One WAVE per row (no block-level sync). 4 rows per 256-thread block.
// Rows [0, B*S) = head, [B*S, 2*B*S) = dep.
// ---------------------------------------------------------------------------
__global__ __launch_bounds__(256) void cast_proj_kernel(
    const float* __restrict__ head, const float* __restrict__ dep,
    const float* __restrict__ edge_W,
    bf16* __restrict__ head_b, bf16* __restrict__ dep_b,
    float* __restrict__ s_head, float* __restrict__ s_dep)
{
    int wid  = threadIdx.x >> 6;
    int lane = threadIdx.x & 63;
    int row  = blockIdx.x * 4 + wid;

    const float* src;
    bf16* dst;
    const float* w;
    float* sout;
    if (row < B_DIM * S_DIM) {
        src  = head   + (size_t)row * D_DIM;
        dst  = head_b + (size_t)row * D_DIM;
        w    = edge_W;             // w[:D]
        sout = s_head + row;
    } else {
        int r = row - B_DIM * S_DIM;
        src  = dep   + (size_t)r * D_DIM;
        dst  = dep_b + (size_t)r * D_DIM;
        w    = edge_W + D_DIM;     // w[D:]
        sout = s_dep + r;
    }

    float d = 0.0f;
    #pragma unroll
    for (int it = 0; it < 4; ++it) {
        int idx = it * 64 + lane;              // float4 index, 256 per row
        float4 v  = ((const float4*)src)[idx];
        float4 wv = ((const float4*)w)[idx];
        bf16x4 o;
        o[0] = (bf16)v.x; o[1] = (bf16)v.y; o[2] = (bf16)v.z; o[3] = (bf16)v.w;
        ((bf16x4*)dst)[idx] = o;
        d += v.x * wv.x + v.y * wv.y + v.z * wv.z + v.w * wv.w;
    }
    #pragma unroll
    for (int off = 32; off > 0; off >>= 1)
        d += __shfl_down(d, off, 64);
    if (lane == 0) *sout = d;
}

// ---------------------------------------------------------------------------
// Kernel 2: Ut[k][d] = (bf16) U[d][k]
// ---------------------------------------------------------------------------
__global__ __launch_bounds__(256) void transpose_cast_U(
    const float* __restrict__ U, bf16* __restrict__ Ut)
{
    __shared__ float tile[32][33];
    int bx = blockIdx.x * 32;
    int by = blockIdx.y * 32;
    int tx = threadIdx.x & 31;
    int ty4 = (threadIdx.x >> 5) * 4;
    #pragma unroll
    for (int i = 0; i < 4; ++i)
        tile[ty4 + i][tx] = U[(size_t)(by + ty4 + i) * D_DIM + bx + tx];
    __syncthreads();
    #pragma unroll
    for (int i = 0; i < 4; ++i)
        Ut[(size_t)(bx + ty4 + i) * D_DIM + by + tx] = (bf16)tile[tx][ty4 + i];
}

// ---------------------------------------------------------------------------
// Pipelined GEMM: C[m][n] = sum_k A[m][k] * Bt[n][k], K = 1024 fixed.
// 128x128 tile, BK=64, 256 threads (2x2 waves), 16x16x32 bf16 MFMA.
// Double-buffered LDS + prefetch-1 with PARTIAL vmcnt waits (never drain
// to 0 inside the loop) via raw s_barrier — removes the m97 barrier-drain.
// XOR-swizzled LDS granules: staging picks global granule cg = slot^(row&7)
// so ds_read_b128 readers (slot = gk^(row&7)) spread over all 32 banks.
// EPI=0: store bf16.  EPI=1: store fp32 + s_row[m] + s_col[n] + bias.
// ---------------------------------------------------------------------------
template <int EPI>
__global__ __launch_bounds__(256, 2) void gemm_bt_kernel(
    const bf16* __restrict__ A, const bf16* __restrict__ Bt,
    void* __restrict__ Cout,
    int N,
    long long sA, long long sB, long long sC,
    const float* __restrict__ s_row, const float* __restrict__ s_col,
    const float* __restrict__ bias)
{
    const int BK = 64;
    const int KITER = D_DIM / BK;          // 16
    __shared__ bf16 As[2][128 * BK];       // 2 x 16 KB
    __shared__ bf16 Bs[2][128 * BK];       // 2 x 16 KB

    int tid  = threadIdx.x;
    int wid  = tid >> 6;
    int lane = tid & 63;
    int quad = lane >> 4;
    int l16  = lane & 15;
    int wr   = wid >> 1;
    int wc   = wid & 1;

    int tile_m = blockIdx.y * 128;
    int tile_n = blockIdx.x * 128;
    int bz     = blockIdx.z;

    const bf16* Ab = A  + (size_t)bz * sA + (size_t)tile_m * D_DIM;
    const bf16* Bb = Bt + (size_t)bz * sB + (size_t)tile_n * D_DIM;

    floatx4 zero = {0.0f, 0.0f, 0.0f, 0.0f};
    floatx4 acc[4][4];
    #pragma unroll
    for (int i = 0; i < 4; ++i)
        #pragma unroll
        for (int j = 0; j < 4; ++j) acc[i][j] = zero;

    // stage one BK-slab into buffer `buf`; 8 global_load_lds per wave
    auto stage = [&](int k0, int buf) {
        #pragma unroll
        for (int it = 0; it < 4; ++it) {
            int g  = wid * 256 + it * 64 + lane;   // granule id 0..1023
            int r  = g >> 3;                       // tile row
            int cg = (g & 7) ^ (r & 7);            // swizzled global granule
            int ldsoff = (wid * 256 + it * 64) * 8;  // wave-uniform, elems
            async_copy16(Ab + (size_t)r * D_DIM + k0 + cg * 8, &As[buf][ldsoff]);
            async_copy16(Bb + (size_t)r * D_DIM + k0 + cg * 8, &Bs[buf][ldsoff]);
        }
    };

    auto compute = [&](int buf) {
        #pragma unroll
        for (int kk = 0; kk < BK; kk += 32) {
            bf16x8 a[4], b[4];
            #pragma unroll
            for (int mt = 0; mt < 4; ++mt) {
                int row = wr * 64 + mt * 16 + l16;
                int slot = ((kk >> 3) + quad) ^ (row & 7);
                a[mt] = *(const bf16x8*)&As[buf][row * BK + slot * 8];
            }
            #pragma unroll
            for (int nt = 0; nt < 4; ++nt) {
                int row = wc * 64 + nt * 16 + l16;
                int slot = ((kk >> 3) + quad) ^ (row & 7);
                b[nt] = *(const bf16x8*)&Bs[buf][row * BK + slot * 8];
            }
            #pragma unroll
            for (int mt = 0; mt < 4; ++mt)
                #pragma unroll
                for (int nt = 0; nt < 4; ++nt)
                    acc[mt][nt] = __builtin_amdgcn_mfma_f32_16x16x32_bf16(
                        a[mt], b[nt], acc[mt][nt], 0, 0, 0);
        }
    };

    stage(0, 0);
    #pragma unroll 2
    for (int k = 0; k < KITER - 1; ++k) {
        int buf = k & 1;
        stage((k + 1) * BK, buf ^ 1);          // prefetch next slab
        // wait only the OLDER 8 loads (this buf); prefetch stays in flight
        asm volatile("s_waitcnt vmcnt(8)\n\ts_barrier" ::: "memory");
        compute(buf);
        // all waves done reading `buf` before next iter overwrites it
        asm volatile("s_barrier" ::: "memory");
    }
    asm volatile("s_waitcnt vmcnt(0)\n\ts_barrier" ::: "memory");
    compute((KITER - 1) & 1);

    // ---- epilogue: C/D layout col = lane&15, row = quad*4 + reg ----
    int row0 = tile_m + wr * 64;
    int col0 = tile_n + wc * 64;
    if (EPI == 0) {
        bf16* Cb = (bf16*)Cout + (size_t)bz * sC;
        #pragma unroll
        for (int mt = 0; mt < 4; ++mt)
            #pragma unroll
            for (int r = 0; r < 4; ++r) {
                int row = row0 + mt * 16 + quad * 4 + r;
                #pragma unroll
                for (int nt = 0; nt < 4; ++nt) {
                    int col = col0 + nt * 16 + l16;
                    Cb[(size_t)row * N + col] = (bf16)acc[mt][nt][r];
                }
            }
    } else {
        float* Cf = (float*)Cout + (size_t)bz * sC;
        float b0 = bias[0];
        const float* srow = s_row + (size_t)bz * S_DIM;
        const float* scol = s_col + (size_t)bz * S_DIM;
        #pragma unroll
        for (int mt = 0; mt < 4; ++mt)
            #pragma unroll
            for (int r = 0; r < 4; ++r) {
                int row = row0 + mt * 16 + quad * 4 + r;
                float sh = srow[row] + b0;
                #pragma unroll
                for (int nt = 0; nt < 4; ++nt) {
                    int col = col0 + nt * 16 + l16;
                    Cf[(size_t)row * N + col] = acc[mt][nt][r] + sh + scol[col];
                }
            }
    }
}

// ---------------------------------------------------------------------------
extern "C" void kernel_launch(void* const* d_in, const int* in_sizes, int n_in,
                              void* d_out, int out_size, void* d_ws, size_t ws_size,
                              hipStream_t stream) {
    const float* head   = (const float*)d_in[0];
    const float* dep    = (const float*)d_in[1];
    const float* edge_U = (const float*)d_in[2];
    const float* edge_W = (const float*)d_in[3];
    const float* edge_b = (const float*)d_in[4];
    float* out = (float*)d_out;

    char* ws = (char*)d_ws;
    const size_t nBSD = (size_t)B_DIM * S_DIM * D_DIM;

    bf16*  head_b = (bf16*)ws;  ws += nBSD * sizeof(bf16);
    bf16*  dep_b  = (bf16*)ws;  ws += nBSD * sizeof(bf16);
    bf16*  Ut     = (bf16*)ws;  ws += (size_t)D_DIM * D_DIM * sizeof(bf16);
    bf16*  tmp_b  = (bf16*)ws;  ws += nBSD * sizeof(bf16);
    float* s_head = (float*)ws; ws += (size_t)B_DIM * S_DIM * sizeof(float);
    float* s_dep  = (float*)ws; ws += (size_t)B_DIM * S_DIM * sizeof(float);

    // 1. cast + projections (one wave per row)
    cast_proj_kernel<<<2 * B_DIM * S_DIM / 4, 256, 0, stream>>>(
        head, dep, edge_W, head_b, dep_b, s_head, s_dep);

    // 2. U^T cast
    transpose_cast_U<<<dim3(32, 32), 256, 0, stream>>>(edge_U, Ut);

    // 3. tmp[b,i,k] = head[b,i,:] @ U  ->  [8192 x 1024] x Ut^T
    gemm_bt_kernel<0><<<dim3(D_DIM / 128, (B_DIM * S_DIM) / 128, 1), 256, 0, stream>>>(
        head_b, Ut, tmp_b, D_DIM,
        0, 0, 0, nullptr, nullptr, nullptr);

    // 4. out[b,i,j] = tmp[b,i,:] @ dep[b,j,:]^T + s_head + s_dep + bias
    gemm_bt_kernel<1><<<dim3(S_DIM / 128, S_DIM / 128, B_DIM), 256, 0, stream>>>(
        tmp_b, dep_b, out, S_DIM,
        (long long)S_DIM * D_DIM, (long long)S_DIM * D_DIM,
        (long long)S_DIM * S_DIM,
        s_head, s_dep, edge_b);
}